// Round 1
// baseline (347.884 us; speedup 1.0000x reference)
//
#include <hip/hip_runtime.h>
#include <hip/hip_fp16.h>

namespace {

constexpr int kFeat = 32;
constexpr int kNA = 64;
constexpr int kNE = 32;
constexpr int kGridElems = kFeat * kNA * kNE;   // 65536
constexpr int kPoleElems = kFeat * 2;           // 64
constexpr int kCols = kNA * kNE;                // 2048 grid columns
constexpr int kColS = kCols;                    // pole-south column index
constexpr int kColN = kCols + 1;                // pole-north column index
constexpr int kTotCols = kCols + 2;             // 2050

constexpr float kPi  = 3.14159265358979323846f;
constexpr float kPi2 = 1.57079632679489661923f;
constexpr float kOmegaAz = 0.09817477042468103f;   // 2*pi/64
constexpr float kOmegaEl = 0.09519977738150889f;   // pi/33
constexpr float kInvOmegaAz = 10.18591635788130f;  // 64/(2*pi)
constexpr float kInvOmegaEl = 10.50422624406509f;  // 33/pi
constexpr float kInvSinAz = 10.20229703f;          // 1/sin(2*pi/64)
constexpr float kInvSinEl = 10.52010966f;          // 1/sin(pi/33)

// Prepass: grid [F][A][E] fp32 -> gt [A*E + 2][F] fp16 (a feature column is
// one contiguous 64B cache line); poles appended as columns 2048/2049.
__global__ __launch_bounds__(256) void transpose_grid_h(
    const float* __restrict__ g, const float* __restrict__ poles,
    __half* __restrict__ gt) {
  int idx = blockIdx.x * 256 + threadIdx.x;
  if (idx < kGridElems) {
    int f = idx >> 11;       // / (NA*NE)
    int ae = idx & 2047;     // a*NE + e
    gt[ae * kFeat + f] = __float2half(g[idx]);
  }
  if (idx < kPoleElems) {
    int f = idx >> 1;
    int p = idx & 1;
    gt[(kCols + p) * kFeat + f] = __float2half(poles[idx]);
  }
}

struct PointSetup {
  int col_bl, col_br, col_tl, col_tr;
  float a1, a2, b1, b2;
};

__device__ __forceinline__ PointSetup setup_point(float az, float el) {
  PointSetup s;
  // azimuth bucket: ar = smallest k with tick_az[k] >= az; ticks at -pi + k*omega
  float ta = (az + kPi) * kInvOmegaAz;
  int ar0 = (int)ceilf(ta);
  int al = ar0 - 1;
  int ar = (ar0 >= kNA) ? 0 : ar0;
  if (al < 0) al = kNA - 1;
  float theta_a = az - (-kPi + (float)al * kOmegaAz);
  float w1a = __sinf(kOmegaAz - theta_a) * kInvSinAz;
  float w2a = __sinf(theta_a) * kInvSinAz;

  // elevation: er = searchsorted(interior ticks at -pi/2 + (k+1)*omega_el)
  float ue = (el + kPi2) * kInvOmegaEl;
  int er = (int)ceilf(ue) - 1;
  er = min(max(er, 0), kNE);
  bool south = (er == 0);
  bool north = (er == kNE);
  int eil = min(max(er - 1, 0), kNE - 1);
  int eir = min(er, kNE - 1);
  float base = south ? -kPi2 : (-kPi2 + (float)(eil + 1) * kOmegaEl);
  float theta_e = el - base;
  float w1e = __sinf(kOmegaEl - theta_e) * kInvSinEl;
  float w2e = __sinf(theta_e) * kInvSinEl;

  s.col_bl = al * kNE + eil;
  s.col_br = ar * kNE + eil;
  s.col_tl = al * kNE + eir;
  s.col_tr = ar * kNE + eir;
  s.a1 = w1e * w1a; s.a2 = w1e * w2a;
  s.b1 = w2e * w1a; s.b2 = w2e * w2a;
  // Pole redirect: exact pole value via two identical half-weight columns
  // (NORMALIZED=False, weights need not sum to 1).
  if (south) {
    s.col_bl = kColS; s.col_br = kColS;
    s.a1 = 0.5f * w1e; s.a2 = s.a1;
  }
  if (north) {
    s.col_tl = kColN; s.col_tr = kColN;
    s.b1 = 0.5f * w2e; s.b2 = s.b1;
  }
  return s;
}

// 4 lanes per point; lane j loads the 16B half-quad j (features 8j..8j+7,
// fp16) of each of the 4 columns. A gather instr covers 16 whole 64B columns;
// a store instr covers 4 fully-written 64B lines (16 consecutive points x 4
// feature rows).
//
// NT policy: out stores and pts loads are non-temporal (evict-first in L2)
// so the 256 MB write stream + 16 MB point stream do not evict the 128 KB
// gather table from the per-XCD L2s. The gt gathers stay default-cached.
__global__ __launch_bounds__(256) void interp_h(
    const float* __restrict__ pts, const __half* __restrict__ gt,
    float* __restrict__ out, int n) {
  int slot = blockIdx.x * 256 + threadIdx.x;
  int i = slot >> 2;
  int j = slot & 3;
  if (i >= n) return;
  float az = __builtin_nontemporal_load(pts + i);
  float el = __builtin_nontemporal_load(pts + n + i);
  PointSetup s = setup_point(az, el);

  union H8 { uint4 u; __half2 h[4]; };
  H8 bl, br, tl, tr;
  int off = j * 8;
  bl.u = *(const uint4*)(gt + s.col_bl * kFeat + off);
  br.u = *(const uint4*)(gt + s.col_br * kFeat + off);
  tl.u = *(const uint4*)(gt + s.col_tl * kFeat + off);
  tr.u = *(const uint4*)(gt + s.col_tr * kFeat + off);

  float acc[8];
#pragma unroll
  for (int q = 0; q < 4; ++q) {
    float2 vbl = __half22float2(bl.h[q]);
    float2 vbr = __half22float2(br.h[q]);
    float2 vtl = __half22float2(tl.h[q]);
    float2 vtr = __half22float2(tr.h[q]);
    acc[2 * q + 0] = s.a1 * vbl.x + s.a2 * vbr.x + s.b1 * vtl.x + s.b2 * vtr.x;
    acc[2 * q + 1] = s.a1 * vbl.y + s.a2 * vbr.y + s.b1 * vtl.y + s.b2 * vtr.y;
  }

  size_t sn = (size_t)n;
  float* o = out + (size_t)(8 * j) * sn + i;
#pragma unroll
  for (int k = 0; k < 8; ++k)
    __builtin_nontemporal_store(acc[k], o + (size_t)k * sn);
}

// Fallback if the workspace is too small for the transposed fp16 grid:
// gather directly from the [F][A][E] layout (scalar strided loads).
__global__ __launch_bounds__(256) void interp_d(
    const float* __restrict__ pts, const float* __restrict__ g,
    const float* __restrict__ poles, float* __restrict__ out, int n) {
  int i = blockIdx.x * 256 + threadIdx.x;
  if (i >= n) return;
  float az = pts[i];
  float el = pts[n + i];
  PointSetup s = setup_point(az, el);

  float a1 = s.a1, a2 = s.a2, b1 = s.b1, b2 = s.b2;
  float pw0 = 0.0f, pw1 = 0.0f;
  if (s.col_bl == kColS) { pw0 = a1 + a2; a1 = 0.0f; a2 = 0.0f; }
  if (s.col_tl == kColN) { pw1 = b1 + b2; b1 = 0.0f; b2 = 0.0f; }

  const float* gbl = g + (s.col_bl < kCols ? s.col_bl : 0);
  const float* gbr = g + (s.col_br < kCols ? s.col_br : 0);
  const float* gtl = g + (s.col_tl < kCols ? s.col_tl : 0);
  const float* gtr = g + (s.col_tr < kCols ? s.col_tr : 0);
  size_t sn = (size_t)n;
#pragma unroll 8
  for (int f = 0; f < kFeat; ++f) {
    float v = a1 * gbl[f * kCols] + a2 * gbr[f * kCols]
            + b1 * gtl[f * kCols] + b2 * gtr[f * kCols]
            + pw0 * poles[f * 2 + 0] + pw1 * poles[f * 2 + 1];
    out[(size_t)f * sn + i] = v;
  }
}

}  // namespace

extern "C" void kernel_launch(void* const* d_in, const int* in_sizes, int n_in,
                              void* d_out, int out_size, void* d_ws, size_t ws_size,
                              hipStream_t stream) {
  (void)n_in; (void)out_size;
  const float* pts   = (const float*)d_in[0];
  const float* grid  = (const float*)d_in[1];
  const float* poles = (const float*)d_in[2];
  float* out = (float*)d_out;
  int n = in_sizes[0] / 2;

  size_t need = (size_t)(kTotCols * kFeat) * sizeof(__half);
  if (ws_size >= need) {
    __half* gt = (__half*)d_ws;
    transpose_grid_h<<<(kGridElems + 255) / 256, 256, 0, stream>>>(grid, poles, gt);
    long long slots = 4LL * n;
    int blocks = (int)((slots + 255) / 256);
    interp_h<<<blocks, 256, 0, stream>>>(pts, gt, out, n);
  } else {
    int blocks = (n + 255) / 256;
    interp_d<<<blocks, 256, 0, stream>>>(pts, grid, poles, out, n);
  }
}

// Round 2
// 316.064 us; speedup vs baseline: 1.1007x; 1.1007x over previous
//
#include <hip/hip_runtime.h>
#include <hip/hip_fp16.h>

namespace {

constexpr int kFeat = 32;
constexpr int kNA = 64;
constexpr int kNE = 32;
constexpr int kGridElems = kFeat * kNA * kNE;   // 65536
constexpr int kPoleElems = kFeat * 2;           // 64
constexpr int kCols = kNA * kNE;                // 2048 grid columns
constexpr int kColS = kCols;                    // pole-south column index
constexpr int kColN = kCols + 1;                // pole-north column index
constexpr int kTotCols = kCols + 2;             // 2050

constexpr float kPi  = 3.14159265358979323846f;
constexpr float kPi2 = 1.57079632679489661923f;
constexpr float kOmegaAz = 0.09817477042468103f;   // 2*pi/64
constexpr float kOmegaEl = 0.09519977738150889f;   // pi/33
constexpr float kInvOmegaAz = 10.18591635788130f;  // 64/(2*pi)
constexpr float kInvOmegaEl = 10.50422624406509f;  // 33/pi
constexpr float kInvSinAz = 10.20229703f;          // 1/sin(2*pi/64)
constexpr float kInvSinEl = 10.52010966f;          // 1/sin(pi/33)

// Prepass: grid [F][A][E] fp32 -> gt [A*E + 2][F] fp16 (a feature column is
// one contiguous 64B cache line); poles appended as columns 2048/2049.
__global__ __launch_bounds__(256) void transpose_grid_h(
    const float* __restrict__ g, const float* __restrict__ poles,
    __half* __restrict__ gt) {
  int idx = blockIdx.x * 256 + threadIdx.x;
  if (idx < kGridElems) {
    int f = idx >> 11;       // / (NA*NE)
    int ae = idx & 2047;     // a*NE + e
    gt[ae * kFeat + f] = __float2half(g[idx]);
  }
  if (idx < kPoleElems) {
    int f = idx >> 1;
    int p = idx & 1;
    gt[(kCols + p) * kFeat + f] = __float2half(poles[idx]);
  }
}

struct PointSetup {
  int col_bl, col_br, col_tl, col_tr;
  float a1, a2, b1, b2;
};

__device__ __forceinline__ PointSetup setup_point(float az, float el) {
  PointSetup s;
  // azimuth bucket: ar = smallest k with tick_az[k] >= az; ticks at -pi + k*omega
  float ta = (az + kPi) * kInvOmegaAz;
  int ar0 = (int)ceilf(ta);
  int al = ar0 - 1;
  int ar = (ar0 >= kNA) ? 0 : ar0;
  if (al < 0) al = kNA - 1;
  float theta_a = az - (-kPi + (float)al * kOmegaAz);
  float w1a = __sinf(kOmegaAz - theta_a) * kInvSinAz;
  float w2a = __sinf(theta_a) * kInvSinAz;

  // elevation: er = searchsorted(interior ticks at -pi/2 + (k+1)*omega_el)
  float ue = (el + kPi2) * kInvOmegaEl;
  int er = (int)ceilf(ue) - 1;
  er = min(max(er, 0), kNE);
  bool south = (er == 0);
  bool north = (er == kNE);
  int eil = min(max(er - 1, 0), kNE - 1);
  int eir = min(er, kNE - 1);
  float base = south ? -kPi2 : (-kPi2 + (float)(eil + 1) * kOmegaEl);
  float theta_e = el - base;
  float w1e = __sinf(kOmegaEl - theta_e) * kInvSinEl;
  float w2e = __sinf(theta_e) * kInvSinEl;

  s.col_bl = al * kNE + eil;
  s.col_br = ar * kNE + eil;
  s.col_tl = al * kNE + eir;
  s.col_tr = ar * kNE + eir;
  s.a1 = w1e * w1a; s.a2 = w1e * w2a;
  s.b1 = w2e * w1a; s.b2 = w2e * w2a;
  // Pole redirect: exact pole value via two identical half-weight columns
  // (NORMALIZED=False, weights need not sum to 1).
  if (south) {
    s.col_bl = kColS; s.col_br = kColS;
    s.a1 = 0.5f * w1e; s.a2 = s.a1;
  }
  if (north) {
    s.col_tl = kColN; s.col_tr = kColN;
    s.b1 = 0.5f * w2e; s.b2 = s.b1;
  }
  return s;
}

__device__ __forceinline__ void gather_cols(
    const __half* __restrict__ gt, const PointSetup& s, int j,
    uint4& bl, uint4& br, uint4& tl, uint4& tr) {
  int off = j * 8;
  bl = *(const uint4*)(gt + s.col_bl * kFeat + off);
  br = *(const uint4*)(gt + s.col_br * kFeat + off);
  tl = *(const uint4*)(gt + s.col_tl * kFeat + off);
  tr = *(const uint4*)(gt + s.col_tr * kFeat + off);
}

__device__ __forceinline__ void compute_store(
    const PointSetup& s, const uint4& blu, const uint4& bru,
    const uint4& tlu, const uint4& tru, int i, int j,
    float* __restrict__ out, size_t sn) {
  union H8 { uint4 u; __half2 h[4]; };
  H8 bl, br, tl, tr;
  bl.u = blu; br.u = bru; tl.u = tlu; tr.u = tru;
  float acc[8];
#pragma unroll
  for (int q = 0; q < 4; ++q) {
    float2 vbl = __half22float2(bl.h[q]);
    float2 vbr = __half22float2(br.h[q]);
    float2 vtl = __half22float2(tl.h[q]);
    float2 vtr = __half22float2(tr.h[q]);
    acc[2 * q + 0] = s.a1 * vbl.x + s.a2 * vbr.x + s.b1 * vtl.x + s.b2 * vtr.x;
    acc[2 * q + 1] = s.a1 * vbl.y + s.a2 * vbr.y + s.b1 * vtl.y + s.b2 * vtr.y;
  }
  float* o = out + (size_t)(8 * j) * sn + i;
#pragma unroll
  for (int k = 0; k < 8; ++k) o[(size_t)k * sn] = acc[k];
}

// 4 lanes per point; lane j handles the 16B half-quad j (features 8j..8j+7)
// of each of the 4 gathered columns. Each thread processes kPPT=4 slots via a
// 2-deep software pipeline: all 4 stages' pts loads issue up front, and the
// gather batch for stage g+1 is issued before stage g's compute+store, so two
// gather batches are always in flight and HBM/L2 latency hides under the
// previous stage's ~300 cycles of VALU+store work. Slot map slot = t0 + g*T
// keeps each wave iteration on 16 consecutive points (fully coalesced
// 4x64B gathers and 4x64B store segments, as in the one-shot version).
constexpr int kPPT = 4;

__global__ __launch_bounds__(256) void interp_h(
    const float* __restrict__ pts, const __half* __restrict__ gt,
    float* __restrict__ out, int n) {
  const long long T = (long long)gridDim.x * 256;
  const long long t0 = (long long)blockIdx.x * 256 + threadIdx.x;
  const long long nslots = 4LL * n;
  const size_t sn = (size_t)n;

  const long long sA = t0;
  const long long sB = t0 + T;
  const long long sC = t0 + 2 * T;
  const long long sD = t0 + 3 * T;
  const bool vA = sA < nslots, vB = sB < nslots, vC = sC < nslots, vD = sD < nslots;
  const int iA = (int)(sA >> 2), jA = (int)(sA & 3);
  const int iB = (int)(sB >> 2), jB = (int)(sB & 3);
  const int iC = (int)(sC >> 2), jC = (int)(sC & 3);
  const int iD = (int)(sD >> 2), jD = (int)(sD & 3);

  // Batch all pts loads up front: 8 independent loads in flight at once.
  float azA = 0.f, elA = 0.f, azB = 0.f, elB = 0.f;
  float azC = 0.f, elC = 0.f, azD = 0.f, elD = 0.f;
  if (vA) { azA = pts[iA]; elA = pts[n + iA]; }
  if (vB) { azB = pts[iB]; elB = pts[n + iB]; }
  if (vC) { azC = pts[iC]; elC = pts[n + iC]; }
  if (vD) { azD = pts[iD]; elD = pts[n + iD]; }

  PointSetup st0, st1;
  uint4 bl0, br0, tl0, tr0, bl1, br1, tl1, tr1;

  // Prologue: issue gathers for stages A and B.
  if (vA) { st0 = setup_point(azA, elA); gather_cols(gt, st0, jA, bl0, br0, tl0, tr0); }
  if (vB) { st1 = setup_point(azB, elB); gather_cols(gt, st1, jB, bl1, br1, tl1, tr1); }

  // Steady state: compute g while gathers for g+1 are in flight.
  if (vA) compute_store(st0, bl0, br0, tl0, tr0, iA, jA, out, sn);
  if (vC) { st0 = setup_point(azC, elC); gather_cols(gt, st0, jC, bl0, br0, tl0, tr0); }

  if (vB) compute_store(st1, bl1, br1, tl1, tr1, iB, jB, out, sn);
  if (vD) { st1 = setup_point(azD, elD); gather_cols(gt, st1, jD, bl1, br1, tl1, tr1); }

  if (vC) compute_store(st0, bl0, br0, tl0, tr0, iC, jC, out, sn);
  if (vD) compute_store(st1, bl1, br1, tl1, tr1, iD, jD, out, sn);
}

// Fallback if the workspace is too small for the transposed fp16 grid:
// gather directly from the [F][A][E] layout (scalar strided loads).
__global__ __launch_bounds__(256) void interp_d(
    const float* __restrict__ pts, const float* __restrict__ g,
    const float* __restrict__ poles, float* __restrict__ out, int n) {
  int i = blockIdx.x * 256 + threadIdx.x;
  if (i >= n) return;
  float az = pts[i];
  float el = pts[n + i];
  PointSetup s = setup_point(az, el);

  float a1 = s.a1, a2 = s.a2, b1 = s.b1, b2 = s.b2;
  float pw0 = 0.0f, pw1 = 0.0f;
  if (s.col_bl == kColS) { pw0 = a1 + a2; a1 = 0.0f; a2 = 0.0f; }
  if (s.col_tl == kColN) { pw1 = b1 + b2; b1 = 0.0f; b2 = 0.0f; }

  const float* gbl = g + (s.col_bl < kCols ? s.col_bl : 0);
  const float* gbr = g + (s.col_br < kCols ? s.col_br : 0);
  const float* gtl = g + (s.col_tl < kCols ? s.col_tl : 0);
  const float* gtr = g + (s.col_tr < kCols ? s.col_tr : 0);
  size_t sn = (size_t)n;
#pragma unroll 8
  for (int f = 0; f < kFeat; ++f) {
    float v = a1 * gbl[f * kCols] + a2 * gbr[f * kCols]
            + b1 * gtl[f * kCols] + b2 * gtr[f * kCols]
            + pw0 * poles[f * 2 + 0] + pw1 * poles[f * 2 + 1];
    out[(size_t)f * sn + i] = v;
  }
}

}  // namespace

extern "C" void kernel_launch(void* const* d_in, const int* in_sizes, int n_in,
                              void* d_out, int out_size, void* d_ws, size_t ws_size,
                              hipStream_t stream) {
  (void)n_in; (void)out_size;
  const float* pts   = (const float*)d_in[0];
  const float* grid  = (const float*)d_in[1];
  const float* poles = (const float*)d_in[2];
  float* out = (float*)d_out;
  int n = in_sizes[0] / 2;

  size_t need = (size_t)(kTotCols * kFeat) * sizeof(__half);
  if (ws_size >= need) {
    __half* gt = (__half*)d_ws;
    transpose_grid_h<<<(kGridElems + 255) / 256, 256, 0, stream>>>(grid, poles, gt);
    long long slots = 4LL * n;
    long long threads = (slots + kPPT - 1) / kPPT;
    int blocks = (int)((threads + 255) / 256);
    interp_h<<<blocks, 256, 0, stream>>>(pts, gt, out, n);
  } else {
    int blocks = (n + 255) / 256;
    interp_d<<<blocks, 256, 0, stream>>>(pts, grid, poles, out, n);
  }
}